// Round 5
// baseline (107190.405 us; speedup 1.0000x reference)
//
#include <hip/hip_runtime.h>
#include <stdint.h>

#define KNB   16
#define GD    64                    // grid cells per axis
#define GTOT  (GD * GD * GD)        // 262144 cells
#define GORIG (-6.5f)
#define GEDGE 0.203125f             // 13.0 / 64
#define GINV  (1.0f / GEDGE)
#define CAPW  640                   // per-query candidate capacity (10 x 64)

typedef short short8 __attribute__((ext_vector_type(8)));
typedef float floatx4 __attribute__((ext_vector_type(4)));

__device__ __forceinline__ unsigned short f2bf(float x) {
  union { float f; uint32_t u; } v; v.f = x;
  uint32_t u = v.u + 0x7FFFu + ((v.u >> 16) & 1u);   // RNE
  return (unsigned short)(u >> 16);
}
__device__ __forceinline__ float bf2f(unsigned short b) {
  return __uint_as_float(((uint32_t)b) << 16);
}
__device__ __forceinline__ int cellco(float v) {
  int c = (int)floorf((v - GORIG) * GINV);
  return c < 0 ? 0 : (c > GD - 1 ? GD - 1 : c);
}

// ---------------------------------------------------------------------------
// zero: count[GTOT] = 0  (must run before prep's atomics, every launch)
// ---------------------------------------------------------------------------
__global__ void zero_kernel(int* __restrict__ count) {
  int i = (blockIdx.x * 256 + threadIdx.x) * 4;
  *(int4*)(count + i) = make_int4(0, 0, 0, 0);
}

// ---------------------------------------------------------------------------
// prep: xb = bf16(x); pos4 = {x,y,z,pp}; ptcell[j] + count atomics; Wt.
// ---------------------------------------------------------------------------
__global__ void prep_kernel(const float* __restrict__ x,
                            const float* __restrict__ pos,
                            const float* __restrict__ W_att,
                            unsigned short* __restrict__ xb,
                            float4* __restrict__ pos4,
                            unsigned short* __restrict__ Wt,
                            int* __restrict__ ptcell,
                            int* __restrict__ count, int N) {
  int id = blockIdx.x * 256 + threadIdx.x;
  int nx8 = N * 8;
  if (id < nx8) {
    const float4* src = (const float4*)x + (size_t)id * 2;
    float4 a = src[0], b = src[1];
    short8 v;
    v[0] = (short)f2bf(a.x); v[1] = (short)f2bf(a.y);
    v[2] = (short)f2bf(a.z); v[3] = (short)f2bf(a.w);
    v[4] = (short)f2bf(b.x); v[5] = (short)f2bf(b.y);
    v[6] = (short)f2bf(b.z); v[7] = (short)f2bf(b.w);
    *(short8*)(xb + (size_t)id * 8) = v;
  } else if (id < nx8 + N) {
    int j = id - nx8;
    float px = pos[3 * j], py = pos[3 * j + 1], pz = pos[3 * j + 2];
    float pp = fmaf(px, px, fmaf(py, py, pz * pz));
    pos4[j] = make_float4(px, py, pz, pp);
    int cid = (cellco(pz) * GD + cellco(py)) * GD + cellco(px);
    ptcell[j] = cid;
    atomicAdd(&count[cid], 1);
  } else if (id < nx8 + N + 128 * 128) {
    int t = id - nx8 - N;
    int c = t >> 7, f = t & 127;
    Wt[f * 128 + c] = f2bf(W_att[t]);
  }
}

// ---------------------------------------------------------------------------
// two-level exclusive scan of count[GTOT] -> cell_start / cursor
// ---------------------------------------------------------------------------
__global__ __launch_bounds__(256) void scan1(const int* __restrict__ count,
                                             int* __restrict__ partial) {
  int b = blockIdx.x, t = threadIdx.x;
  int v = count[b * 256 + t];
#pragma unroll
  for (int off = 1; off < 64; off <<= 1) v += __shfl_xor(v, off);
  __shared__ int ws_[4];
  if ((t & 63) == 0) ws_[t >> 6] = v;
  __syncthreads();
  if (t == 0) partial[b] = ws_[0] + ws_[1] + ws_[2] + ws_[3];
}

__global__ __launch_bounds__(256) void scan2(int* __restrict__ partial,
                                             int* __restrict__ cell_start) {
  int t = threadIdx.x;
  int v0 = partial[t * 4], v1 = partial[t * 4 + 1];
  int v2 = partial[t * 4 + 2], v3 = partial[t * 4 + 3];
  int s1 = v0 + v1, s2 = s1 + v2, s3 = s2 + v3;
  int x = s3;
  int lane = t & 63, wv = t >> 6;
#pragma unroll
  for (int off = 1; off < 64; off <<= 1) {
    int y = __shfl_up(x, off);
    if (lane >= off) x += y;
  }
  __shared__ int wsum[4];
  if (lane == 63) wsum[wv] = x;
  __syncthreads();
  int base = 0;
  for (int k = 0; k < wv; ++k) base += wsum[k];
  int excl = base + x - s3;
  partial[t * 4]     = excl;
  partial[t * 4 + 1] = excl + v0;
  partial[t * 4 + 2] = excl + s1;
  partial[t * 4 + 3] = excl + s2;
  if (t == 255) cell_start[GTOT] = excl + s3;   // = N
}

__global__ __launch_bounds__(256) void scan3(const int* __restrict__ count,
                                             const int* __restrict__ partial,
                                             int* __restrict__ cell_start,
                                             int* __restrict__ cursor) {
  int b = blockIdx.x, t = threadIdx.x;
  int v = count[b * 256 + t];
  int x = v;
  int lane = t & 63, wv = t >> 6;
#pragma unroll
  for (int off = 1; off < 64; off <<= 1) {
    int y = __shfl_up(x, off);
    if (lane >= off) x += y;
  }
  __shared__ int wsum[4];
  if (lane == 63) wsum[wv] = x;
  __syncthreads();
  int base = partial[b];
  for (int k = 0; k < wv; ++k) base += wsum[k];
  int excl = base + x - v;
  cell_start[b * 256 + t] = excl;
  cursor[b * 256 + t] = excl;
}

// ---------------------------------------------------------------------------
// scatter: points into cell-sorted order (spos4 + original index sid)
// ---------------------------------------------------------------------------
__global__ void scatter_kernel(const float4* __restrict__ pos4,
                               const int* __restrict__ ptcell,
                               int* __restrict__ cursor,
                               float4* __restrict__ spos4,
                               int* __restrict__ sid, int N) {
  int j = blockIdx.x * 256 + threadIdx.x;
  if (j >= N) return;
  int cid = ptcell[j];
  int slot = atomicAdd(&cursor[cid], 1);
  spos4[slot] = pos4[j];
  sid[slot] = j;
}

// ---------------------------------------------------------------------------
// knn_grid: one wave per query. Expanding Chebyshev shells; exact f32 d2
// stored as packed (d2bits<<32|idx) in LDS (same key/tie-break as proven p3).
// Terminate when >=16 stored points lie within r_expl = distance to the
// unexplored region (grid-clamped sides are infinite: edge cells hold all
// outliers on that side). Extraction = verbatim p3 extract-min.
// ---------------------------------------------------------------------------
__global__ __launch_bounds__(256) void knn_grid(
    const float4* __restrict__ pos4, const float4* __restrict__ spos4,
    const int* __restrict__ sid, const int* __restrict__ cell_start,
    const int* __restrict__ idx, int* __restrict__ nbr, int M) {
  __shared__ unsigned long long cand[4][CAPW];
  const int tid = threadIdx.x, wv = tid >> 6, ln = tid & 63;
  const int m = blockIdx.x * 4 + wv;
  if (m >= M) return;

  const float4 qp = pos4[idx[m]];
  const int cqx = cellco(qp.x), cqy = cellco(qp.y), cqz = cellco(qp.z);

  int tot = 0;
  bool done = false;
  for (int s = 0; s <= 66 && !done; ++s) {
    const int w = 2 * s + 1, wsq = w * w, ncell = wsq * w;
    for (int base = 0; base < ncell; base += 64) {
      int i = base + ln;
      int st = 0, en = 0;
      if (i < ncell) {
        int iz = i / wsq;
        int rem = i - iz * wsq;
        int iy = rem / w;
        int ix = rem - iy * w;
        int dz = iz - s, dy = iy - s, dx = ix - s;
        int az = dz < 0 ? -dz : dz, ay = dy < 0 ? -dy : dy,
            ax = dx < 0 ? -dx : dx;
        int ch = az > ay ? az : ay; ch = ch > ax ? ch : ax;
        int cz = cqz + dz, cy = cqy + dy, cx = cqx + dx;
        if (ch == s && cz >= 0 && cz < GD && cy >= 0 && cy < GD &&
            cx >= 0 && cx < GD) {
          int cid = (cz * GD + cy) * GD + cx;
          st = cell_start[cid];
          en = cell_start[cid + 1];
        }
      }
      unsigned long long mk = __ballot(en > st);
      while (mk) {
        int l = __ffsll((unsigned long long)mk) - 1;
        mk &= mk - 1;
        int stl = __shfl(st, l), enl = __shfl(en, l);
        for (int b2 = stl; b2 < enl; b2 += 64) {
          int p = b2 + ln;
          if (p < enl) {
            float4 pj = spos4[p];
            float dot = fmaf(qp.x, pj.x, fmaf(qp.y, pj.y, qp.z * pj.z));
            float tt  = fmaf(-2.f, dot, pj.w);
            float d2  = fmaxf(qp.w + tt, 0.f);
            int slot = tot + (p - stl);
            if (slot < CAPW)
              cand[wv][slot] =
                  ((unsigned long long)__float_as_uint(d2) << 32) |
                  (uint32_t)sid[p];
          }
        }
        tot += enl - stl;
      }
    }
    // termination: distance from q to unexplored region (clamped side = inf)
    float fx = qp.x - GORIG, fy = qp.y - GORIG, fz = qp.z - GORIG;
    float r = 3.0e38f;
    if (cqx - s > 0)      r = fminf(r, fx - (float)(cqx - s) * GEDGE);
    if (cqx + s < GD - 1) r = fminf(r, (float)(cqx + s + 1) * GEDGE - fx);
    if (cqy - s > 0)      r = fminf(r, fy - (float)(cqy - s) * GEDGE);
    if (cqy + s < GD - 1) r = fminf(r, (float)(cqy + s + 1) * GEDGE - fy);
    if (cqz - s > 0)      r = fminf(r, fz - (float)(cqz - s) * GEDGE);
    if (cqz + s < GD - 1) r = fminf(r, (float)(cqz + s + 1) * GEDGE - fz);
    float r2 = (r > 1.0e19f) ? 3.0e38f : r * r;
    int nc = tot < CAPW ? tot : CAPW;
    int cnt = 0;
#pragma unroll
    for (int chk = 0; chk < CAPW / 64; ++chk) {
      int slot = chk * 64 + ln;
      unsigned long long key = cand[wv][slot];
      float d2v = __uint_as_float((uint32_t)(key >> 32));
      cnt += __popcll(__ballot(slot < nc && d2v <= r2));
    }
    if (cnt >= KNB && tot <= CAPW) done = true;
  }

  // extraction (p3 machinery)
  int nc = tot < CAPW ? tot : CAPW;
  unsigned long long c[CAPW / 64];
#pragma unroll
  for (int chk = 0; chk < CAPW / 64; ++chk) {
    int slot = chk * 64 + ln;
    unsigned long long k2 = cand[wv][slot];
    c[chk] = (slot < nc) ? k2 : ~0ull;
  }
#pragma unroll
  for (int r = 0; r < KNB; ++r) {
    unsigned long long mn = c[0];
#pragma unroll
    for (int chk = 1; chk < CAPW / 64; ++chk) mn = (c[chk] < mn) ? c[chk] : mn;
#pragma unroll
    for (int off = 1; off < 64; off <<= 1) {
      unsigned long long o = __shfl_xor(mn, off);
      mn = (o < mn) ? o : mn;
    }
    if (ln == 0) nbr[m * KNB + r] = (int)(uint32_t)mn;
#pragma unroll
    for (int chk = 0; chk < CAPW / 64; ++chk)
      if (c[chk] == mn) c[chk] = ~0ull;
  }
}

// ---------------------------------------------------------------------------
// mid: 8 queries / 256-thread block (unchanged from passing version).
// ---------------------------------------------------------------------------
__global__ __launch_bounds__(256) void mid_kernel(
    const unsigned short* __restrict__ xb, const float4* __restrict__ pos4,
    const int* __restrict__ idx, const float* __restrict__ W_pos,
    const float* __restrict__ b_pos, const unsigned short* __restrict__ Wt,
    const float* __restrict__ b_att, const int* __restrict__ nbr,
    float* __restrict__ aggr, int M) {
  __shared__ __align__(16) unsigned short fijb[8][16][136];
  __shared__ int nbr_s[128];
  __shared__ float4 qpos_s[8];

  const int tid = threadIdx.x;
  const int wid = tid >> 6, lane = tid & 63;
  const int col = lane & 15, quad = lane >> 4;
  const int b = blockIdx.x;

  if (tid < 128) {
    int mq = b * 8 + (tid >> 4); if (mq >= M) mq = M - 1;
    nbr_s[tid] = nbr[mq * 16 + (tid & 15)];
  }
  if (tid < 8) {
    int mq = b * 8 + tid; if (mq >= M) mq = M - 1;
    qpos_s[tid] = pos4[idx[mq]];
  }
  float wp[10];
#pragma unroll
  for (int t = 0; t < 10; ++t) wp[t] = W_pos[t * 64 + lane];
  float bp = b_pos[lane];
  __syncthreads();

  {
    int rr = tid >> 1, h = tid & 1;
    int jn = nbr_s[rr];
    const short8* src = (const short8*)(xb + ((size_t)jn << 6) + (h << 5));
    short8 v0 = src[0], v1 = src[1], v2 = src[2], v3 = src[3];
    short8* dst = (short8*)&fijb[rr >> 4][rr & 15][h * 32];
    dst[0] = v0; dst[1] = v1; dst[2] = v2; dst[3] = v3;
  }
#pragma unroll
  for (int qi = 0; qi < 2; ++qi) {
    int q = wid * 2 + qi;
    float4 qp = qpos_s[q];
#pragma unroll 4
    for (int k = 0; k < 16; ++k) {
      int jn = nbr_s[q * 16 + k];
      float4 pj = pos4[jn];
      float vx = qp.x - pj.x, vy = qp.y - pj.y, vz = qp.z - pj.z;
      float dd = sqrtf(fmaf(vx, vx, fmaf(vy, vy, vz * vz)));
      float r = bp;
      r = fmaf(qp.x, wp[0], r); r = fmaf(qp.y, wp[1], r); r = fmaf(qp.z, wp[2], r);
      r = fmaf(pj.x, wp[3], r); r = fmaf(pj.y, wp[4], r); r = fmaf(pj.z, wp[5], r);
      r = fmaf(vx, wp[6], r);  r = fmaf(vy, wp[7], r);  r = fmaf(vz, wp[8], r);
      r = fmaf(dd, wp[9], r);
      r = fmaxf(r, 0.f);
      fijb[q][k][64 + lane] = f2bf(r);
    }
  }
  __syncthreads();

#pragma unroll 1
  for (int qi = 0; qi < 2; ++qi) {
    int q = wid * 2 + qi;
    int mq = b * 8 + q;

    short8 af[4];
#pragma unroll
    for (int cs = 0; cs < 4; ++cs)
      af[cs] = *(const short8*)&fijb[q][col][cs * 32 + quad * 8];

    floatx4 acc[8];
#pragma unroll
    for (int ft = 0; ft < 8; ++ft) {
      float bav = b_att[ft * 16 + col];
      floatx4 a = {bav, bav, bav, bav};
#pragma unroll
      for (int cs = 0; cs < 4; ++cs) {
        short8 bfrag =
            *(const short8*)&Wt[(ft * 16 + col) * 128 + cs * 32 + quad * 8];
        a = __builtin_amdgcn_mfma_f32_16x16x32_bf16(af[cs], bfrag, a, 0, 0, 0);
      }
      acc[ft] = a;
    }

    float rowmax[4], rowinv[4];
#pragma unroll
    for (int r = 0; r < 4; ++r) {
      float mx = acc[0][r];
#pragma unroll
      for (int ft = 1; ft < 8; ++ft) mx = fmaxf(mx, acc[ft][r]);
      mx = fmaxf(mx, __shfl_xor(mx, 1));
      mx = fmaxf(mx, __shfl_xor(mx, 2));
      mx = fmaxf(mx, __shfl_xor(mx, 4));
      mx = fmaxf(mx, __shfl_xor(mx, 8));
      float sm = 0.f;
#pragma unroll
      for (int ft = 0; ft < 8; ++ft) sm += __expf(acc[ft][r] - mx);
      sm += __shfl_xor(sm, 1);
      sm += __shfl_xor(sm, 2);
      sm += __shfl_xor(sm, 4);
      sm += __shfl_xor(sm, 8);
      rowmax[r] = mx;
      rowinv[r] = 1.0f / sm;
    }

#pragma unroll
    for (int ft = 0; ft < 8; ++ft) {
      float ap = 0.f;
#pragma unroll
      for (int r = 0; r < 4; ++r) {
        float s = __expf(acc[ft][r] - rowmax[r]) * rowinv[r];
        float fv = bf2f(fijb[q][quad * 4 + r][ft * 16 + col]);
        ap = fmaf(s, fv, ap);
      }
      ap += __shfl_xor(ap, 16);
      ap += __shfl_xor(ap, 32);
      if (quad == 0 && mq < M)
        aggr[mq * 128 + ft * 16 + col] = ap * (1.0f / 16.0f);
    }
  }
}

// ---------------------------------------------------------------------------
// out = relu(aggr @ W_glob + b_glob)
// ---------------------------------------------------------------------------
__global__ __launch_bounds__(256) void out_kernel(
    const float* __restrict__ aggr, const float* __restrict__ W_glob,
    const float* __restrict__ b_glob, float* __restrict__ out, int M) {
  __shared__ float ag[16][128];
  const int tid = threadIdx.x;
  const int mbase = blockIdx.x * 16;
  for (int s = tid; s < 16 * 128; s += 256) {
    int r = s >> 7, cc = s & 127;
    int m = mbase + r;
    ((float*)ag)[s] = (m < M) ? aggr[m * 128 + cc] : 0.0f;
  }
  __syncthreads();
  const int f = tid & 127, h = tid >> 7;
  float acc[8];
  float bg = b_glob[f];
#pragma unroll
  for (int i = 0; i < 8; ++i) acc[i] = bg;
  for (int c = 0; c < 128; c += 4) {
    float w0 = W_glob[(c + 0) * 128 + f];
    float w1 = W_glob[(c + 1) * 128 + f];
    float w2 = W_glob[(c + 2) * 128 + f];
    float w3 = W_glob[(c + 3) * 128 + f];
#pragma unroll
    for (int i = 0; i < 8; ++i) {
      const floatx4 a4 = *(const floatx4*)&ag[h * 8 + i][c];
      acc[i] += a4[0] * w0 + a4[1] * w1 + a4[2] * w2 + a4[3] * w3;
    }
  }
#pragma unroll
  for (int i = 0; i < 8; ++i) {
    int m = mbase + h * 8 + i;
    if (m < M) out[m * 128 + f] = fmaxf(acc[i], 0.0f);
  }
}

// ---------------------------------------------------------------------------
extern "C" void kernel_launch(void* const* d_in, const int* in_sizes, int n_in,
                              void* d_out, int out_size, void* d_ws,
                              size_t ws_size, hipStream_t stream) {
  const float* x      = (const float*)d_in[0];
  const float* pos    = (const float*)d_in[1];
  const int*   idx    = (const int*)d_in[2];
  const float* W_pos  = (const float*)d_in[3];
  const float* b_pos  = (const float*)d_in[4];
  const float* W_att  = (const float*)d_in[5];
  const float* b_att  = (const float*)d_in[6];
  const float* W_glob = (const float*)d_in[7];
  const float* b_glob = (const float*)d_in[8];
  float* out = (float*)d_out;

  const int N = in_sizes[1] / 3;
  const int M = in_sizes[2];

  char* ws = (char*)d_ws;
  size_t o = 0;
  float4* pos4 = (float4*)(ws + o);               o += ((size_t)N * 16 + 255) & ~(size_t)255;
  unsigned short* xb = (unsigned short*)(ws + o); o += ((size_t)N * 128 + 255) & ~(size_t)255;
  unsigned short* Wt = (unsigned short*)(ws + o); o += (128 * 128 * 2 + 255) & ~(size_t)255;
  int* nbr = (int*)(ws + o);                      o += (((size_t)M * KNB * 4) + 255) & ~(size_t)255;
  int* ptcell = (int*)(ws + o);                   o += (((size_t)N * 4) + 255) & ~(size_t)255;
  int* count = (int*)(ws + o);                    o += ((size_t)GTOT * 4 + 255) & ~(size_t)255;
  int* cursor = (int*)(ws + o);                   o += ((size_t)GTOT * 4 + 255) & ~(size_t)255;
  int* cell_start = (int*)(ws + o);               o += ((size_t)(GTOT + 1) * 4 + 255) & ~(size_t)255;
  int* partial = (int*)(ws + o);                  o += (1024 * 4 + 255) & ~(size_t)255;
  float4* spos4 = (float4*)(ws + o);              o += ((size_t)N * 16 + 255) & ~(size_t)255;
  int* sid = (int*)(ws + o);                      o += (((size_t)N * 4) + 255) & ~(size_t)255;
  float* aggr = (float*)(ws + o);                 o += ((size_t)M * 128 * 4 + 255) & ~(size_t)255;

  zero_kernel<<<GTOT / 1024, 256, 0, stream>>>(count);

  int prep_ids = N * 8 + N + 128 * 128;
  prep_kernel<<<(prep_ids + 255) / 256, 256, 0, stream>>>(
      x, pos, W_att, xb, pos4, Wt, ptcell, count, N);

  scan1<<<GTOT / 256, 256, 0, stream>>>(count, partial);
  scan2<<<1, 256, 0, stream>>>(partial, cell_start);
  scan3<<<GTOT / 256, 256, 0, stream>>>(count, partial, cell_start, cursor);

  scatter_kernel<<<(N + 255) / 256, 256, 0, stream>>>(pos4, ptcell, cursor,
                                                      spos4, sid, N);

  knn_grid<<<(M + 3) / 4, 256, 0, stream>>>(pos4, spos4, sid, cell_start, idx,
                                            nbr, M);

  mid_kernel<<<(M + 7) / 8, 256, 0, stream>>>(xb, pos4, idx, W_pos, b_pos, Wt,
                                              b_att, nbr, aggr, M);
  out_kernel<<<(M + 15) / 16, 256, 0, stream>>>(aggr, W_glob, b_glob, out, M);
}

// Round 6
// 416.492 us; speedup vs baseline: 257.3647x; 257.3647x over previous
//
#include <hip/hip_runtime.h>
#include <stdint.h>

#define KNB   16
#define GD    64                    // grid cells per axis
#define GTOT  (GD * GD * GD)        // 262144 cells
#define GORIG (-6.5f)
#define GEDGE 0.203125f             // 13.0 / 64
#define GINV  (1.0f / GEDGE)
#define CAPW  640                   // per-query candidate capacity (10 x 64)

typedef short short8 __attribute__((ext_vector_type(8)));
typedef float floatx4 __attribute__((ext_vector_type(4)));

__device__ __forceinline__ unsigned short f2bf(float x) {
  union { float f; uint32_t u; } v; v.f = x;
  uint32_t u = v.u + 0x7FFFu + ((v.u >> 16) & 1u);   // RNE
  return (unsigned short)(u >> 16);
}
__device__ __forceinline__ float bf2f(unsigned short b) {
  return __uint_as_float(((uint32_t)b) << 16);
}
__device__ __forceinline__ int cellco(float v) {
  int c = (int)floorf((v - GORIG) * GINV);
  return c < 0 ? 0 : (c > GD - 1 ? GD - 1 : c);
}

// ---------------------------------------------------------------------------
// zero: count[GTOT] = 0  (must run before prep's atomics, every launch)
// ---------------------------------------------------------------------------
__global__ void zero_kernel(int* __restrict__ count) {
  int i = (blockIdx.x * 256 + threadIdx.x) * 4;
  *(int4*)(count + i) = make_int4(0, 0, 0, 0);
}

// ---------------------------------------------------------------------------
// prep: xb = bf16(x); pos4 = {x,y,z,pp}; ptcell[j] + count atomics; Wt.
// ---------------------------------------------------------------------------
__global__ void prep_kernel(const float* __restrict__ x,
                            const float* __restrict__ pos,
                            const float* __restrict__ W_att,
                            unsigned short* __restrict__ xb,
                            float4* __restrict__ pos4,
                            unsigned short* __restrict__ Wt,
                            int* __restrict__ ptcell,
                            int* __restrict__ count, int N) {
  int id = blockIdx.x * 256 + threadIdx.x;
  int nx8 = N * 8;
  if (id < nx8) {
    const float4* src = (const float4*)x + (size_t)id * 2;
    float4 a = src[0], b = src[1];
    short8 v;
    v[0] = (short)f2bf(a.x); v[1] = (short)f2bf(a.y);
    v[2] = (short)f2bf(a.z); v[3] = (short)f2bf(a.w);
    v[4] = (short)f2bf(b.x); v[5] = (short)f2bf(b.y);
    v[6] = (short)f2bf(b.z); v[7] = (short)f2bf(b.w);
    *(short8*)(xb + (size_t)id * 8) = v;
  } else if (id < nx8 + N) {
    int j = id - nx8;
    float px = pos[3 * j], py = pos[3 * j + 1], pz = pos[3 * j + 2];
    float pp = fmaf(px, px, fmaf(py, py, pz * pz));
    pos4[j] = make_float4(px, py, pz, pp);
    int cid = (cellco(pz) * GD + cellco(py)) * GD + cellco(px);
    ptcell[j] = cid;
    atomicAdd(&count[cid], 1);
  } else if (id < nx8 + N + 128 * 128) {
    int t = id - nx8 - N;
    int c = t >> 7, f = t & 127;
    Wt[f * 128 + c] = f2bf(W_att[t]);
  }
}

// ---------------------------------------------------------------------------
// two-level exclusive scan of count[GTOT] -> cell_start / cursor
// ---------------------------------------------------------------------------
__global__ __launch_bounds__(256) void scan1(const int* __restrict__ count,
                                             int* __restrict__ partial) {
  int b = blockIdx.x, t = threadIdx.x;
  int v = count[b * 256 + t];
#pragma unroll
  for (int off = 1; off < 64; off <<= 1) v += __shfl_xor(v, off);
  __shared__ int ws_[4];
  if ((t & 63) == 0) ws_[t >> 6] = v;
  __syncthreads();
  if (t == 0) partial[b] = ws_[0] + ws_[1] + ws_[2] + ws_[3];
}

__global__ __launch_bounds__(256) void scan2(int* __restrict__ partial,
                                             int* __restrict__ cell_start) {
  int t = threadIdx.x;
  int v0 = partial[t * 4], v1 = partial[t * 4 + 1];
  int v2 = partial[t * 4 + 2], v3 = partial[t * 4 + 3];
  int s1 = v0 + v1, s2 = s1 + v2, s3 = s2 + v3;
  int x = s3;
  int lane = t & 63, wv = t >> 6;
#pragma unroll
  for (int off = 1; off < 64; off <<= 1) {
    int y = __shfl_up(x, off);
    if (lane >= off) x += y;
  }
  __shared__ int wsum[4];
  if (lane == 63) wsum[wv] = x;
  __syncthreads();
  int base = 0;
  for (int k = 0; k < wv; ++k) base += wsum[k];
  int excl = base + x - s3;
  partial[t * 4]     = excl;
  partial[t * 4 + 1] = excl + v0;
  partial[t * 4 + 2] = excl + s1;
  partial[t * 4 + 3] = excl + s2;
  if (t == 255) cell_start[GTOT] = excl + s3;   // = N
}

__global__ __launch_bounds__(256) void scan3(const int* __restrict__ count,
                                             const int* __restrict__ partial,
                                             int* __restrict__ cell_start,
                                             int* __restrict__ cursor) {
  int b = blockIdx.x, t = threadIdx.x;
  int v = count[b * 256 + t];
  int x = v;
  int lane = t & 63, wv = t >> 6;
#pragma unroll
  for (int off = 1; off < 64; off <<= 1) {
    int y = __shfl_up(x, off);
    if (lane >= off) x += y;
  }
  __shared__ int wsum[4];
  if (lane == 63) wsum[wv] = x;
  __syncthreads();
  int base = partial[b];
  for (int k = 0; k < wv; ++k) base += wsum[k];
  int excl = base + x - v;
  cell_start[b * 256 + t] = excl;
  cursor[b * 256 + t] = excl;
}

// ---------------------------------------------------------------------------
// scatter: points into cell-sorted order (spos4 + original index sid)
// ---------------------------------------------------------------------------
__global__ void scatter_kernel(const float4* __restrict__ pos4,
                               const int* __restrict__ ptcell,
                               int* __restrict__ cursor,
                               float4* __restrict__ spos4,
                               int* __restrict__ sid, int N) {
  int j = blockIdx.x * 256 + threadIdx.x;
  if (j >= N) return;
  int cid = ptcell[j];
  int slot = atomicAdd(&cursor[cid], 1);
  spos4[slot] = pos4[j];
  sid[slot] = j;
}

// ---------------------------------------------------------------------------
// knn_grid: one wave per query. Expanding Chebyshev shells; exact f32 d2
// stored as packed (d2bits<<32|idx) in LDS (same key/tie-break as proven p3).
// NEW (R6): bounded storage. Before draining a cell that would overflow CAPW,
// compact stored set to its exact top-16 (taukey = 16th key); afterwards only
// keys < taukey are stored (exact: >=16 better candidates already stored).
// Invariant: stored set always contains the true running top-16 and
// tot <= CAPW -> termination (cnt-within-r_expl >= 16) always reachable.
// Extraction = verbatim proven extract-min.
// ---------------------------------------------------------------------------
__global__ __launch_bounds__(256) void knn_grid(
    const float4* __restrict__ pos4, const float4* __restrict__ spos4,
    const int* __restrict__ sid, const int* __restrict__ cell_start,
    const int* __restrict__ idx, int* __restrict__ nbr, int M) {
  __shared__ unsigned long long cand[4][CAPW];
  const int tid = threadIdx.x, wv = tid >> 6, ln = tid & 63;
  const int m = blockIdx.x * 4 + wv;
  if (m >= M) return;

  const float4 qp = pos4[idx[m]];
  const int cqx = cellco(qp.x), cqy = cellco(qp.y), cqz = cellco(qp.z);

  int tot = 0;
  unsigned long long taukey = ~0ull;   // store filter (max until capped)
  bool done = false;
  for (int s = 0; s <= 64 && !done; ++s) {
    const int w = 2 * s + 1, wsq = w * w, ncell = wsq * w;
    for (int base = 0; base < ncell; base += 64) {
      int i = base + ln;
      int st = 0, en = 0;
      if (i < ncell) {
        int iz = i / wsq;
        int rem = i - iz * wsq;
        int iy = rem / w;
        int ix = rem - iy * w;
        int dz = iz - s, dy = iy - s, dx = ix - s;
        int az = dz < 0 ? -dz : dz, ay = dy < 0 ? -dy : dy,
            ax = dx < 0 ? -dx : dx;
        int ch = az > ay ? az : ay; ch = ch > ax ? ch : ax;
        int cz = cqz + dz, cy = cqy + dy, cx = cqx + dx;
        if (ch == s && cz >= 0 && cz < GD && cy >= 0 && cy < GD &&
            cx >= 0 && cx < GD) {
          int cid = (cz * GD + cy) * GD + cx;
          st = cell_start[cid];
          en = cell_start[cid + 1];
        }
      }
      unsigned long long mk = __ballot(en > st);
      while (mk) {
        int l = __ffsll((unsigned long long)mk) - 1;
        mk &= mk - 1;
        int stl = __shfl(st, l), enl = __shfl(en, l);

        // --- compaction: keep exact top-16, set taukey, free space ---
        if (tot + (enl - stl) > CAPW) {
          int nc = tot;
          unsigned long long c[CAPW / 64];
#pragma unroll
          for (int chk = 0; chk < CAPW / 64; ++chk) {
            int slot = chk * 64 + ln;
            c[chk] = (slot < nc) ? cand[wv][slot] : ~0ull;
          }
          unsigned long long last = 0;
#pragma unroll
          for (int r = 0; r < KNB; ++r) {
            unsigned long long mn = c[0];
#pragma unroll
            for (int chk = 1; chk < CAPW / 64; ++chk)
              mn = (c[chk] < mn) ? c[chk] : mn;
#pragma unroll
            for (int off = 1; off < 64; off <<= 1) {
              unsigned long long o = __shfl_xor(mn, off);
              mn = (o < mn) ? o : mn;
            }
            if (ln == 0) cand[wv][r] = mn;   // c[] already in registers
            last = mn;
#pragma unroll
            for (int chk = 0; chk < CAPW / 64; ++chk)
              if (c[chk] == mn) c[chk] = ~0ull;
          }
          tot = KNB;
          taukey = last;
        }

        // --- drain cell with ballot+prefix slot assignment ---
        for (int b2 = stl; b2 < enl; b2 += 64) {
          int p = b2 + ln;
          unsigned long long key = ~0ull;
          bool ok = false;
          if (p < enl) {
            float4 pj = spos4[p];
            float dot = fmaf(qp.x, pj.x, fmaf(qp.y, pj.y, qp.z * pj.z));
            float tt  = fmaf(-2.f, dot, pj.w);
            float d2  = fmaxf(qp.w + tt, 0.f);
            key = ((unsigned long long)__float_as_uint(d2) << 32) |
                  (uint32_t)sid[p];
            ok = key < taukey;
          }
          unsigned long long bm = __ballot(ok);
          int pos = __popcll(bm & ((1ull << ln) - 1ull));
          if (ok) cand[wv][tot + pos] = key;
          tot += __popcll(bm);
        }
      }
    }
    // termination: distance from q to unexplored region (clamped side = inf)
    if (tot >= KNB) {
      float fx = qp.x - GORIG, fy = qp.y - GORIG, fz = qp.z - GORIG;
      float r = 3.0e38f;
      if (cqx - s > 0)      r = fminf(r, fx - (float)(cqx - s) * GEDGE);
      if (cqx + s < GD - 1) r = fminf(r, (float)(cqx + s + 1) * GEDGE - fx);
      if (cqy - s > 0)      r = fminf(r, fy - (float)(cqy - s) * GEDGE);
      if (cqy + s < GD - 1) r = fminf(r, (float)(cqy + s + 1) * GEDGE - fy);
      if (cqz - s > 0)      r = fminf(r, fz - (float)(cqz - s) * GEDGE);
      if (cqz + s < GD - 1) r = fminf(r, (float)(cqz + s + 1) * GEDGE - fz);
      float r2 = (r > 1.0e19f) ? 3.0e38f : r * r;
      int nc = tot;
      int cnt = 0;
#pragma unroll
      for (int chk = 0; chk < CAPW / 64; ++chk) {
        int slot = chk * 64 + ln;
        unsigned long long key = cand[wv][slot];
        float d2v = __uint_as_float((uint32_t)(key >> 32));
        cnt += __popcll(__ballot(slot < nc && d2v <= r2));
      }
      if (cnt >= KNB) done = true;
    }
  }

  // extraction (proven machinery)
  int nc = tot;
  unsigned long long c[CAPW / 64];
#pragma unroll
  for (int chk = 0; chk < CAPW / 64; ++chk) {
    int slot = chk * 64 + ln;
    unsigned long long k2 = cand[wv][slot];
    c[chk] = (slot < nc) ? k2 : ~0ull;
  }
#pragma unroll
  for (int r = 0; r < KNB; ++r) {
    unsigned long long mn = c[0];
#pragma unroll
    for (int chk = 1; chk < CAPW / 64; ++chk) mn = (c[chk] < mn) ? c[chk] : mn;
#pragma unroll
    for (int off = 1; off < 64; off <<= 1) {
      unsigned long long o = __shfl_xor(mn, off);
      mn = (o < mn) ? o : mn;
    }
    if (ln == 0) nbr[m * KNB + r] = (int)(uint32_t)mn;
#pragma unroll
    for (int chk = 0; chk < CAPW / 64; ++chk)
      if (c[chk] == mn) c[chk] = ~0ull;
  }
}

// ---------------------------------------------------------------------------
// mid: 8 queries / 256-thread block (unchanged from passing version).
// ---------------------------------------------------------------------------
__global__ __launch_bounds__(256) void mid_kernel(
    const unsigned short* __restrict__ xb, const float4* __restrict__ pos4,
    const int* __restrict__ idx, const float* __restrict__ W_pos,
    const float* __restrict__ b_pos, const unsigned short* __restrict__ Wt,
    const float* __restrict__ b_att, const int* __restrict__ nbr,
    float* __restrict__ aggr, int M) {
  __shared__ __align__(16) unsigned short fijb[8][16][136];
  __shared__ int nbr_s[128];
  __shared__ float4 qpos_s[8];

  const int tid = threadIdx.x;
  const int wid = tid >> 6, lane = tid & 63;
  const int col = lane & 15, quad = lane >> 4;
  const int b = blockIdx.x;

  if (tid < 128) {
    int mq = b * 8 + (tid >> 4); if (mq >= M) mq = M - 1;
    nbr_s[tid] = nbr[mq * 16 + (tid & 15)];
  }
  if (tid < 8) {
    int mq = b * 8 + tid; if (mq >= M) mq = M - 1;
    qpos_s[tid] = pos4[idx[mq]];
  }
  float wp[10];
#pragma unroll
  for (int t = 0; t < 10; ++t) wp[t] = W_pos[t * 64 + lane];
  float bp = b_pos[lane];
  __syncthreads();

  {
    int rr = tid >> 1, h = tid & 1;
    int jn = nbr_s[rr];
    const short8* src = (const short8*)(xb + ((size_t)jn << 6) + (h << 5));
    short8 v0 = src[0], v1 = src[1], v2 = src[2], v3 = src[3];
    short8* dst = (short8*)&fijb[rr >> 4][rr & 15][h * 32];
    dst[0] = v0; dst[1] = v1; dst[2] = v2; dst[3] = v3;
  }
#pragma unroll
  for (int qi = 0; qi < 2; ++qi) {
    int q = wid * 2 + qi;
    float4 qp = qpos_s[q];
#pragma unroll 4
    for (int k = 0; k < 16; ++k) {
      int jn = nbr_s[q * 16 + k];
      float4 pj = pos4[jn];
      float vx = qp.x - pj.x, vy = qp.y - pj.y, vz = qp.z - pj.z;
      float dd = sqrtf(fmaf(vx, vx, fmaf(vy, vy, vz * vz)));
      float r = bp;
      r = fmaf(qp.x, wp[0], r); r = fmaf(qp.y, wp[1], r); r = fmaf(qp.z, wp[2], r);
      r = fmaf(pj.x, wp[3], r); r = fmaf(pj.y, wp[4], r); r = fmaf(pj.z, wp[5], r);
      r = fmaf(vx, wp[6], r);  r = fmaf(vy, wp[7], r);  r = fmaf(vz, wp[8], r);
      r = fmaf(dd, wp[9], r);
      r = fmaxf(r, 0.f);
      fijb[q][k][64 + lane] = f2bf(r);
    }
  }
  __syncthreads();

#pragma unroll 1
  for (int qi = 0; qi < 2; ++qi) {
    int q = wid * 2 + qi;
    int mq = b * 8 + q;

    short8 af[4];
#pragma unroll
    for (int cs = 0; cs < 4; ++cs)
      af[cs] = *(const short8*)&fijb[q][col][cs * 32 + quad * 8];

    floatx4 acc[8];
#pragma unroll
    for (int ft = 0; ft < 8; ++ft) {
      float bav = b_att[ft * 16 + col];
      floatx4 a = {bav, bav, bav, bav};
#pragma unroll
      for (int cs = 0; cs < 4; ++cs) {
        short8 bfrag =
            *(const short8*)&Wt[(ft * 16 + col) * 128 + cs * 32 + quad * 8];
        a = __builtin_amdgcn_mfma_f32_16x16x32_bf16(af[cs], bfrag, a, 0, 0, 0);
      }
      acc[ft] = a;
    }

    float rowmax[4], rowinv[4];
#pragma unroll
    for (int r = 0; r < 4; ++r) {
      float mx = acc[0][r];
#pragma unroll
      for (int ft = 1; ft < 8; ++ft) mx = fmaxf(mx, acc[ft][r]);
      mx = fmaxf(mx, __shfl_xor(mx, 1));
      mx = fmaxf(mx, __shfl_xor(mx, 2));
      mx = fmaxf(mx, __shfl_xor(mx, 4));
      mx = fmaxf(mx, __shfl_xor(mx, 8));
      float sm = 0.f;
#pragma unroll
      for (int ft = 0; ft < 8; ++ft) sm += __expf(acc[ft][r] - mx);
      sm += __shfl_xor(sm, 1);
      sm += __shfl_xor(sm, 2);
      sm += __shfl_xor(sm, 4);
      sm += __shfl_xor(sm, 8);
      rowmax[r] = mx;
      rowinv[r] = 1.0f / sm;
    }

#pragma unroll
    for (int ft = 0; ft < 8; ++ft) {
      float ap = 0.f;
#pragma unroll
      for (int r = 0; r < 4; ++r) {
        float s = __expf(acc[ft][r] - rowmax[r]) * rowinv[r];
        float fv = bf2f(fijb[q][quad * 4 + r][ft * 16 + col]);
        ap = fmaf(s, fv, ap);
      }
      ap += __shfl_xor(ap, 16);
      ap += __shfl_xor(ap, 32);
      if (quad == 0 && mq < M)
        aggr[mq * 128 + ft * 16 + col] = ap * (1.0f / 16.0f);
    }
  }
}

// ---------------------------------------------------------------------------
// out = relu(aggr @ W_glob + b_glob)
// ---------------------------------------------------------------------------
__global__ __launch_bounds__(256) void out_kernel(
    const float* __restrict__ aggr, const float* __restrict__ W_glob,
    const float* __restrict__ b_glob, float* __restrict__ out, int M) {
  __shared__ float ag[16][128];
  const int tid = threadIdx.x;
  const int mbase = blockIdx.x * 16;
  for (int s = tid; s < 16 * 128; s += 256) {
    int r = s >> 7, cc = s & 127;
    int m = mbase + r;
    ((float*)ag)[s] = (m < M) ? aggr[m * 128 + cc] : 0.0f;
  }
  __syncthreads();
  const int f = tid & 127, h = tid >> 7;
  float acc[8];
  float bg = b_glob[f];
#pragma unroll
  for (int i = 0; i < 8; ++i) acc[i] = bg;
  for (int c = 0; c < 128; c += 4) {
    float w0 = W_glob[(c + 0) * 128 + f];
    float w1 = W_glob[(c + 1) * 128 + f];
    float w2 = W_glob[(c + 2) * 128 + f];
    float w3 = W_glob[(c + 3) * 128 + f];
#pragma unroll
    for (int i = 0; i < 8; ++i) {
      const floatx4 a4 = *(const floatx4*)&ag[h * 8 + i][c];
      acc[i] += a4[0] * w0 + a4[1] * w1 + a4[2] * w2 + a4[3] * w3;
    }
  }
#pragma unroll
  for (int i = 0; i < 8; ++i) {
    int m = mbase + h * 8 + i;
    if (m < M) out[m * 128 + f] = fmaxf(acc[i], 0.0f);
  }
}

// ---------------------------------------------------------------------------
extern "C" void kernel_launch(void* const* d_in, const int* in_sizes, int n_in,
                              void* d_out, int out_size, void* d_ws,
                              size_t ws_size, hipStream_t stream) {
  const float* x      = (const float*)d_in[0];
  const float* pos    = (const float*)d_in[1];
  const int*   idx    = (const int*)d_in[2];
  const float* W_pos  = (const float*)d_in[3];
  const float* b_pos  = (const float*)d_in[4];
  const float* W_att  = (const float*)d_in[5];
  const float* b_att  = (const float*)d_in[6];
  const float* W_glob = (const float*)d_in[7];
  const float* b_glob = (const float*)d_in[8];
  float* out = (float*)d_out;

  const int N = in_sizes[1] / 3;
  const int M = in_sizes[2];

  char* ws = (char*)d_ws;
  size_t o = 0;
  float4* pos4 = (float4*)(ws + o);               o += ((size_t)N * 16 + 255) & ~(size_t)255;
  unsigned short* xb = (unsigned short*)(ws + o); o += ((size_t)N * 128 + 255) & ~(size_t)255;
  unsigned short* Wt = (unsigned short*)(ws + o); o += (128 * 128 * 2 + 255) & ~(size_t)255;
  int* nbr = (int*)(ws + o);                      o += (((size_t)M * KNB * 4) + 255) & ~(size_t)255;
  int* ptcell = (int*)(ws + o);                   o += (((size_t)N * 4) + 255) & ~(size_t)255;
  int* count = (int*)(ws + o);                    o += ((size_t)GTOT * 4 + 255) & ~(size_t)255;
  int* cursor = (int*)(ws + o);                   o += ((size_t)GTOT * 4 + 255) & ~(size_t)255;
  int* cell_start = (int*)(ws + o);               o += ((size_t)(GTOT + 1) * 4 + 255) & ~(size_t)255;
  int* partial = (int*)(ws + o);                  o += (1024 * 4 + 255) & ~(size_t)255;
  float4* spos4 = (float4*)(ws + o);              o += ((size_t)N * 16 + 255) & ~(size_t)255;
  int* sid = (int*)(ws + o);                      o += (((size_t)N * 4) + 255) & ~(size_t)255;
  float* aggr = (float*)(ws + o);                 o += ((size_t)M * 128 * 4 + 255) & ~(size_t)255;

  zero_kernel<<<GTOT / 1024, 256, 0, stream>>>(count);

  int prep_ids = N * 8 + N + 128 * 128;
  prep_kernel<<<(prep_ids + 255) / 256, 256, 0, stream>>>(
      x, pos, W_att, xb, pos4, Wt, ptcell, count, N);

  scan1<<<GTOT / 256, 256, 0, stream>>>(count, partial);
  scan2<<<1, 256, 0, stream>>>(partial, cell_start);
  scan3<<<GTOT / 256, 256, 0, stream>>>(count, partial, cell_start, cursor);

  scatter_kernel<<<(N + 255) / 256, 256, 0, stream>>>(pos4, ptcell, cursor,
                                                      spos4, sid, N);

  knn_grid<<<(M + 3) / 4, 256, 0, stream>>>(pos4, spos4, sid, cell_start, idx,
                                            nbr, M);

  mid_kernel<<<(M + 7) / 8, 256, 0, stream>>>(xb, pos4, idx, W_pos, b_pos, Wt,
                                              b_att, nbr, aggr, M);
  out_kernel<<<(M + 15) / 16, 256, 0, stream>>>(aggr, W_glob, b_glob, out, M);
}

// Round 7
// 212.016 us; speedup vs baseline: 505.5776x; 1.9644x over previous
//
#include <hip/hip_runtime.h>
#include <stdint.h>

#define KNB   16
#define GD    64                    // grid cells per axis
#define GTOT  (GD * GD * GD)        // 262144 cells
#define GORIG (-6.5f)
#define GEDGE 0.203125f             // 13.0 / 64
#define GINV  (1.0f / GEDGE)
#define CAPW  640                   // per-query candidate capacity (10 x 64)

typedef short short8 __attribute__((ext_vector_type(8)));
typedef float floatx4 __attribute__((ext_vector_type(4)));

__device__ __forceinline__ unsigned short f2bf(float x) {
  union { float f; uint32_t u; } v; v.f = x;
  uint32_t u = v.u + 0x7FFFu + ((v.u >> 16) & 1u);   // RNE
  return (unsigned short)(u >> 16);
}
__device__ __forceinline__ float bf2f(unsigned short b) {
  return __uint_as_float(((uint32_t)b) << 16);
}
__device__ __forceinline__ int cellco(float v) {
  int c = (int)floorf((v - GORIG) * GINV);
  return c < 0 ? 0 : (c > GD - 1 ? GD - 1 : c);
}

// ---------------------------------------------------------------------------
// zero: count[GTOT] = 0  (must run before prep's atomics, every launch)
// ---------------------------------------------------------------------------
__global__ void zero_kernel(int* __restrict__ count) {
  int i = (blockIdx.x * 256 + threadIdx.x) * 4;
  *(int4*)(count + i) = make_int4(0, 0, 0, 0);
}

// ---------------------------------------------------------------------------
// prep: xb = bf16(x); pos4 = {x,y,z,pp}; ptcell[j] + count atomics; Wt.
// ---------------------------------------------------------------------------
__global__ void prep_kernel(const float* __restrict__ x,
                            const float* __restrict__ pos,
                            const float* __restrict__ W_att,
                            unsigned short* __restrict__ xb,
                            float4* __restrict__ pos4,
                            unsigned short* __restrict__ Wt,
                            int* __restrict__ ptcell,
                            int* __restrict__ count, int N) {
  int id = blockIdx.x * 256 + threadIdx.x;
  int nx8 = N * 8;
  if (id < nx8) {
    const float4* src = (const float4*)x + (size_t)id * 2;
    float4 a = src[0], b = src[1];
    short8 v;
    v[0] = (short)f2bf(a.x); v[1] = (short)f2bf(a.y);
    v[2] = (short)f2bf(a.z); v[3] = (short)f2bf(a.w);
    v[4] = (short)f2bf(b.x); v[5] = (short)f2bf(b.y);
    v[6] = (short)f2bf(b.z); v[7] = (short)f2bf(b.w);
    *(short8*)(xb + (size_t)id * 8) = v;
  } else if (id < nx8 + N) {
    int j = id - nx8;
    float px = pos[3 * j], py = pos[3 * j + 1], pz = pos[3 * j + 2];
    float pp = fmaf(px, px, fmaf(py, py, pz * pz));
    pos4[j] = make_float4(px, py, pz, pp);
    int cid = (cellco(pz) * GD + cellco(py)) * GD + cellco(px);
    ptcell[j] = cid;
    atomicAdd(&count[cid], 1);
  } else if (id < nx8 + N + 128 * 128) {
    int t = id - nx8 - N;
    int c = t >> 7, f = t & 127;
    Wt[f * 128 + c] = f2bf(W_att[t]);
  }
}

// ---------------------------------------------------------------------------
// two-level exclusive scan of count[GTOT] -> cell_start / cursor
// ---------------------------------------------------------------------------
__global__ __launch_bounds__(256) void scan1(const int* __restrict__ count,
                                             int* __restrict__ partial) {
  int b = blockIdx.x, t = threadIdx.x;
  int v = count[b * 256 + t];
#pragma unroll
  for (int off = 1; off < 64; off <<= 1) v += __shfl_xor(v, off);
  __shared__ int ws_[4];
  if ((t & 63) == 0) ws_[t >> 6] = v;
  __syncthreads();
  if (t == 0) partial[b] = ws_[0] + ws_[1] + ws_[2] + ws_[3];
}

__global__ __launch_bounds__(256) void scan2(int* __restrict__ partial,
                                             int* __restrict__ cell_start) {
  int t = threadIdx.x;
  int v0 = partial[t * 4], v1 = partial[t * 4 + 1];
  int v2 = partial[t * 4 + 2], v3 = partial[t * 4 + 3];
  int s1 = v0 + v1, s2 = s1 + v2, s3 = s2 + v3;
  int x = s3;
  int lane = t & 63, wv = t >> 6;
#pragma unroll
  for (int off = 1; off < 64; off <<= 1) {
    int y = __shfl_up(x, off);
    if (lane >= off) x += y;
  }
  __shared__ int wsum[4];
  if (lane == 63) wsum[wv] = x;
  __syncthreads();
  int base = 0;
  for (int k = 0; k < wv; ++k) base += wsum[k];
  int excl = base + x - s3;
  partial[t * 4]     = excl;
  partial[t * 4 + 1] = excl + v0;
  partial[t * 4 + 2] = excl + s1;
  partial[t * 4 + 3] = excl + s2;
  if (t == 255) cell_start[GTOT] = excl + s3;   // = N
}

__global__ __launch_bounds__(256) void scan3(const int* __restrict__ count,
                                             const int* __restrict__ partial,
                                             int* __restrict__ cell_start,
                                             int* __restrict__ cursor) {
  int b = blockIdx.x, t = threadIdx.x;
  int v = count[b * 256 + t];
  int x = v;
  int lane = t & 63, wv = t >> 6;
#pragma unroll
  for (int off = 1; off < 64; off <<= 1) {
    int y = __shfl_up(x, off);
    if (lane >= off) x += y;
  }
  __shared__ int wsum[4];
  if (lane == 63) wsum[wv] = x;
  __syncthreads();
  int base = partial[b];
  for (int k = 0; k < wv; ++k) base += wsum[k];
  int excl = base + x - v;
  cell_start[b * 256 + t] = excl;
  cursor[b * 256 + t] = excl;
}

// ---------------------------------------------------------------------------
// scatter: points into cell-sorted order (spos4 + original index sid)
// ---------------------------------------------------------------------------
__global__ void scatter_kernel(const float4* __restrict__ pos4,
                               const int* __restrict__ ptcell,
                               int* __restrict__ cursor,
                               float4* __restrict__ spos4,
                               int* __restrict__ sid, int N) {
  int j = blockIdx.x * 256 + threadIdx.x;
  if (j >= N) return;
  int cid = ptcell[j];
  int slot = atomicAdd(&cursor[cid], 1);
  spos4[slot] = pos4[j];
  sid[slot] = j;
}

// ---------------------------------------------------------------------------
// knn_grid (R7): one wave per query. Shell s enumerated as (2s+1)^2 (dz,dy)
// rows: full contiguous x-row when max(|dz|,|dy|)==s (cells contiguous in
// cid), else two singleton cells at dx=+-s. s=1 drains the whole [-1,1]^3
// cube (shells 0+1) as 9 full rows. Per-64-point overflow check inside the
// drain compacts stored set to its exact top-16 (taukey = 16th key) before
// any store can overflow -> tot <= CAPW invariant holds for any row length.
// Stored set provably always contains the true running top-16; termination
// when >=16 stored lie within r_expl (distance to unexplored region,
// grid-clamped sides = inf). Extraction = verbatim proven extract-min.
// ---------------------------------------------------------------------------
__global__ __launch_bounds__(256) void knn_grid(
    const float4* __restrict__ pos4, const float4* __restrict__ spos4,
    const int* __restrict__ sid, const int* __restrict__ cell_start,
    const int* __restrict__ idx, int* __restrict__ nbr, int M) {
  __shared__ unsigned long long cand[4][CAPW];
  const int tid = threadIdx.x, wv = tid >> 6, ln = tid & 63;
  const int m = blockIdx.x * 4 + wv;
  if (m >= M) return;

  const float4 qp = pos4[idx[m]];
  const int cqx = cellco(qp.x), cqy = cellco(qp.y), cqz = cellco(qp.z);

  int tot = 0;
  unsigned long long taukey = ~0ull;   // store filter (max until first compact)
  bool done = false;
  for (int s = 1; s <= 64 && !done; ++s) {
    const int w = 2 * s + 1, npair = w * w;
    for (int base = 0; base < npair; base += 64) {
      int i = base + ln;
      int stA = 0, enA = 0, stB = 0, enB = 0;
      if (i < npair) {
        int dz = i / w - s, dy = i - (i / w) * w - s;
        int cz = cqz + dz, cy = cqy + dy;
        if (cz >= 0 && cz < GD && cy >= 0 && cy < GD) {
          int rowbase = (cz * GD + cy) * GD;
          int az = dz < 0 ? -dz : dz, ay = dy < 0 ? -dy : dy;
          int ch = az > ay ? az : ay;
          if (s == 1 || ch == s) {
            // full contiguous x-row [cqx-s, cqx+s] clipped
            int x0 = cqx - s; if (x0 < 0) x0 = 0;
            int x1 = cqx + s; if (x1 > GD - 1) x1 = GD - 1;
            stA = cell_start[rowbase + x0];
            enA = cell_start[rowbase + x1 + 1];
          } else {
            // interior row: two singleton cells at dx = -s, +s
            int xl = cqx - s, xr = cqx + s;
            if (xl >= 0) {
              stA = cell_start[rowbase + xl];
              enA = cell_start[rowbase + xl + 1];
            }
            if (xr <= GD - 1) {
              stB = cell_start[rowbase + xr];
              enB = cell_start[rowbase + xr + 1];
            }
          }
        }
      }
#pragma unroll
      for (int part = 0; part < 2; ++part) {
        int st = part ? stB : stA, en = part ? enB : enA;
        unsigned long long mk = __ballot(en > st);
        while (mk) {
          int l = __ffsll((unsigned long long)mk) - 1;
          mk &= mk - 1;
          int stl = __shfl(st, l), enl = __shfl(en, l);
          for (int b2 = stl; b2 < enl; b2 += 64) {
            // --- overflow-proof: compact to exact top-16 before store ---
            if (tot + 64 > CAPW) {
              unsigned long long c[CAPW / 64];
#pragma unroll
              for (int chk = 0; chk < CAPW / 64; ++chk) {
                int slot = chk * 64 + ln;
                c[chk] = (slot < tot) ? cand[wv][slot] : ~0ull;
              }
              unsigned long long last = 0;
#pragma unroll
              for (int r = 0; r < KNB; ++r) {
                unsigned long long mn = c[0];
#pragma unroll
                for (int chk = 1; chk < CAPW / 64; ++chk)
                  mn = (c[chk] < mn) ? c[chk] : mn;
#pragma unroll
                for (int off = 1; off < 64; off <<= 1) {
                  unsigned long long o = __shfl_xor(mn, off);
                  mn = (o < mn) ? o : mn;
                }
                if (ln == 0) cand[wv][r] = mn;
                last = mn;
#pragma unroll
                for (int chk = 0; chk < CAPW / 64; ++chk)
                  if (c[chk] == mn) c[chk] = ~0ull;
              }
              tot = KNB;
              taukey = last;
            }
            int p = b2 + ln;
            unsigned long long key = ~0ull;
            bool ok = false;
            if (p < enl) {
              float4 pj = spos4[p];
              float dot = fmaf(qp.x, pj.x, fmaf(qp.y, pj.y, qp.z * pj.z));
              float tt  = fmaf(-2.f, dot, pj.w);
              float d2  = fmaxf(qp.w + tt, 0.f);
              key = ((unsigned long long)__float_as_uint(d2) << 32) |
                    (uint32_t)sid[p];
              ok = key < taukey;
            }
            unsigned long long bm = __ballot(ok);
            int pos = __popcll(bm & ((1ull << ln) - 1ull));
            if (ok) cand[wv][tot + pos] = key;
            tot += __popcll(bm);
          }
        }
      }
    }
    // termination: distance from q to unexplored region (clamped side = inf)
    if (tot >= KNB) {
      float fx = qp.x - GORIG, fy = qp.y - GORIG, fz = qp.z - GORIG;
      float r = 3.0e38f;
      if (cqx - s > 0)      r = fminf(r, fx - (float)(cqx - s) * GEDGE);
      if (cqx + s < GD - 1) r = fminf(r, (float)(cqx + s + 1) * GEDGE - fx);
      if (cqy - s > 0)      r = fminf(r, fy - (float)(cqy - s) * GEDGE);
      if (cqy + s < GD - 1) r = fminf(r, (float)(cqy + s + 1) * GEDGE - fy);
      if (cqz - s > 0)      r = fminf(r, fz - (float)(cqz - s) * GEDGE);
      if (cqz + s < GD - 1) r = fminf(r, (float)(cqz + s + 1) * GEDGE - fz);
      float r2 = (r > 1.0e19f) ? 3.0e38f : r * r;
      int cnt = 0;
      for (int chk = 0; chk * 64 < tot; ++chk) {
        int slot = chk * 64 + ln;
        unsigned long long key = cand[wv][slot];
        float d2v = __uint_as_float((uint32_t)(key >> 32));
        cnt += __popcll(__ballot(slot < tot && d2v <= r2));
      }
      if (cnt >= KNB) done = true;
    }
  }

  // extraction (proven machinery)
  int nc = tot;
  unsigned long long c[CAPW / 64];
#pragma unroll
  for (int chk = 0; chk < CAPW / 64; ++chk) {
    int slot = chk * 64 + ln;
    unsigned long long k2 = cand[wv][slot];
    c[chk] = (slot < nc) ? k2 : ~0ull;
  }
#pragma unroll
  for (int r = 0; r < KNB; ++r) {
    unsigned long long mn = c[0];
#pragma unroll
    for (int chk = 1; chk < CAPW / 64; ++chk) mn = (c[chk] < mn) ? c[chk] : mn;
#pragma unroll
    for (int off = 1; off < 64; off <<= 1) {
      unsigned long long o = __shfl_xor(mn, off);
      mn = (o < mn) ? o : mn;
    }
    if (ln == 0) nbr[m * KNB + r] = (int)(uint32_t)mn;
#pragma unroll
    for (int chk = 0; chk < CAPW / 64; ++chk)
      if (c[chk] == mn) c[chk] = ~0ull;
  }
}

// ---------------------------------------------------------------------------
// mid: 8 queries / 256-thread block (unchanged from passing version).
// ---------------------------------------------------------------------------
__global__ __launch_bounds__(256) void mid_kernel(
    const unsigned short* __restrict__ xb, const float4* __restrict__ pos4,
    const int* __restrict__ idx, const float* __restrict__ W_pos,
    const float* __restrict__ b_pos, const unsigned short* __restrict__ Wt,
    const float* __restrict__ b_att, const int* __restrict__ nbr,
    float* __restrict__ aggr, int M) {
  __shared__ __align__(16) unsigned short fijb[8][16][136];
  __shared__ int nbr_s[128];
  __shared__ float4 qpos_s[8];

  const int tid = threadIdx.x;
  const int wid = tid >> 6, lane = tid & 63;
  const int col = lane & 15, quad = lane >> 4;
  const int b = blockIdx.x;

  if (tid < 128) {
    int mq = b * 8 + (tid >> 4); if (mq >= M) mq = M - 1;
    nbr_s[tid] = nbr[mq * 16 + (tid & 15)];
  }
  if (tid < 8) {
    int mq = b * 8 + tid; if (mq >= M) mq = M - 1;
    qpos_s[tid] = pos4[idx[mq]];
  }
  float wp[10];
#pragma unroll
  for (int t = 0; t < 10; ++t) wp[t] = W_pos[t * 64 + lane];
  float bp = b_pos[lane];
  __syncthreads();

  {
    int rr = tid >> 1, h = tid & 1;
    int jn = nbr_s[rr];
    const short8* src = (const short8*)(xb + ((size_t)jn << 6) + (h << 5));
    short8 v0 = src[0], v1 = src[1], v2 = src[2], v3 = src[3];
    short8* dst = (short8*)&fijb[rr >> 4][rr & 15][h * 32];
    dst[0] = v0; dst[1] = v1; dst[2] = v2; dst[3] = v3;
  }
#pragma unroll
  for (int qi = 0; qi < 2; ++qi) {
    int q = wid * 2 + qi;
    float4 qp = qpos_s[q];
#pragma unroll 4
    for (int k = 0; k < 16; ++k) {
      int jn = nbr_s[q * 16 + k];
      float4 pj = pos4[jn];
      float vx = qp.x - pj.x, vy = qp.y - pj.y, vz = qp.z - pj.z;
      float dd = sqrtf(fmaf(vx, vx, fmaf(vy, vy, vz * vz)));
      float r = bp;
      r = fmaf(qp.x, wp[0], r); r = fmaf(qp.y, wp[1], r); r = fmaf(qp.z, wp[2], r);
      r = fmaf(pj.x, wp[3], r); r = fmaf(pj.y, wp[4], r); r = fmaf(pj.z, wp[5], r);
      r = fmaf(vx, wp[6], r);  r = fmaf(vy, wp[7], r);  r = fmaf(vz, wp[8], r);
      r = fmaf(dd, wp[9], r);
      r = fmaxf(r, 0.f);
      fijb[q][k][64 + lane] = f2bf(r);
    }
  }
  __syncthreads();

#pragma unroll 1
  for (int qi = 0; qi < 2; ++qi) {
    int q = wid * 2 + qi;
    int mq = b * 8 + q;

    short8 af[4];
#pragma unroll
    for (int cs = 0; cs < 4; ++cs)
      af[cs] = *(const short8*)&fijb[q][col][cs * 32 + quad * 8];

    floatx4 acc[8];
#pragma unroll
    for (int ft = 0; ft < 8; ++ft) {
      float bav = b_att[ft * 16 + col];
      floatx4 a = {bav, bav, bav, bav};
#pragma unroll
      for (int cs = 0; cs < 4; ++cs) {
        short8 bfrag =
            *(const short8*)&Wt[(ft * 16 + col) * 128 + cs * 32 + quad * 8];
        a = __builtin_amdgcn_mfma_f32_16x16x32_bf16(af[cs], bfrag, a, 0, 0, 0);
      }
      acc[ft] = a;
    }

    float rowmax[4], rowinv[4];
#pragma unroll
    for (int r = 0; r < 4; ++r) {
      float mx = acc[0][r];
#pragma unroll
      for (int ft = 1; ft < 8; ++ft) mx = fmaxf(mx, acc[ft][r]);
      mx = fmaxf(mx, __shfl_xor(mx, 1));
      mx = fmaxf(mx, __shfl_xor(mx, 2));
      mx = fmaxf(mx, __shfl_xor(mx, 4));
      mx = fmaxf(mx, __shfl_xor(mx, 8));
      float sm = 0.f;
#pragma unroll
      for (int ft = 0; ft < 8; ++ft) sm += __expf(acc[ft][r] - mx);
      sm += __shfl_xor(sm, 1);
      sm += __shfl_xor(sm, 2);
      sm += __shfl_xor(sm, 4);
      sm += __shfl_xor(sm, 8);
      rowmax[r] = mx;
      rowinv[r] = 1.0f / sm;
    }

#pragma unroll
    for (int ft = 0; ft < 8; ++ft) {
      float ap = 0.f;
#pragma unroll
      for (int r = 0; r < 4; ++r) {
        float s = __expf(acc[ft][r] - rowmax[r]) * rowinv[r];
        float fv = bf2f(fijb[q][quad * 4 + r][ft * 16 + col]);
        ap = fmaf(s, fv, ap);
      }
      ap += __shfl_xor(ap, 16);
      ap += __shfl_xor(ap, 32);
      if (quad == 0 && mq < M)
        aggr[mq * 128 + ft * 16 + col] = ap * (1.0f / 16.0f);
    }
  }
}

// ---------------------------------------------------------------------------
// out = relu(aggr @ W_glob + b_glob)
// ---------------------------------------------------------------------------
__global__ __launch_bounds__(256) void out_kernel(
    const float* __restrict__ aggr, const float* __restrict__ W_glob,
    const float* __restrict__ b_glob, float* __restrict__ out, int M) {
  __shared__ float ag[16][128];
  const int tid = threadIdx.x;
  const int mbase = blockIdx.x * 16;
  for (int s = tid; s < 16 * 128; s += 256) {
    int r = s >> 7, cc = s & 127;
    int m = mbase + r;
    ((float*)ag)[s] = (m < M) ? aggr[m * 128 + cc] : 0.0f;
  }
  __syncthreads();
  const int f = tid & 127, h = tid >> 7;
  float acc[8];
  float bg = b_glob[f];
#pragma unroll
  for (int i = 0; i < 8; ++i) acc[i] = bg;
  for (int c = 0; c < 128; c += 4) {
    float w0 = W_glob[(c + 0) * 128 + f];
    float w1 = W_glob[(c + 1) * 128 + f];
    float w2 = W_glob[(c + 2) * 128 + f];
    float w3 = W_glob[(c + 3) * 128 + f];
#pragma unroll
    for (int i = 0; i < 8; ++i) {
      const floatx4 a4 = *(const floatx4*)&ag[h * 8 + i][c];
      acc[i] += a4[0] * w0 + a4[1] * w1 + a4[2] * w2 + a4[3] * w3;
    }
  }
#pragma unroll
  for (int i = 0; i < 8; ++i) {
    int m = mbase + h * 8 + i;
    if (m < M) out[m * 128 + f] = fmaxf(acc[i], 0.0f);
  }
}

// ---------------------------------------------------------------------------
extern "C" void kernel_launch(void* const* d_in, const int* in_sizes, int n_in,
                              void* d_out, int out_size, void* d_ws,
                              size_t ws_size, hipStream_t stream) {
  const float* x      = (const float*)d_in[0];
  const float* pos    = (const float*)d_in[1];
  const int*   idx    = (const int*)d_in[2];
  const float* W_pos  = (const float*)d_in[3];
  const float* b_pos  = (const float*)d_in[4];
  const float* W_att  = (const float*)d_in[5];
  const float* b_att  = (const float*)d_in[6];
  const float* W_glob = (const float*)d_in[7];
  const float* b_glob = (const float*)d_in[8];
  float* out = (float*)d_out;

  const int N = in_sizes[1] / 3;
  const int M = in_sizes[2];

  char* ws = (char*)d_ws;
  size_t o = 0;
  float4* pos4 = (float4*)(ws + o);               o += ((size_t)N * 16 + 255) & ~(size_t)255;
  unsigned short* xb = (unsigned short*)(ws + o); o += ((size_t)N * 128 + 255) & ~(size_t)255;
  unsigned short* Wt = (unsigned short*)(ws + o); o += (128 * 128 * 2 + 255) & ~(size_t)255;
  int* nbr = (int*)(ws + o);                      o += (((size_t)M * KNB * 4) + 255) & ~(size_t)255;
  int* ptcell = (int*)(ws + o);                   o += (((size_t)N * 4) + 255) & ~(size_t)255;
  int* count = (int*)(ws + o);                    o += ((size_t)GTOT * 4 + 255) & ~(size_t)255;
  int* cursor = (int*)(ws + o);                   o += ((size_t)GTOT * 4 + 255) & ~(size_t)255;
  int* cell_start = (int*)(ws + o);               o += ((size_t)(GTOT + 1) * 4 + 255) & ~(size_t)255;
  int* partial = (int*)(ws + o);                  o += (1024 * 4 + 255) & ~(size_t)255;
  float4* spos4 = (float4*)(ws + o);              o += ((size_t)N * 16 + 255) & ~(size_t)255;
  int* sid = (int*)(ws + o);                      o += (((size_t)N * 4) + 255) & ~(size_t)255;
  float* aggr = (float*)(ws + o);                 o += ((size_t)M * 128 * 4 + 255) & ~(size_t)255;

  zero_kernel<<<GTOT / 1024, 256, 0, stream>>>(count);

  int prep_ids = N * 8 + N + 128 * 128;
  prep_kernel<<<(prep_ids + 255) / 256, 256, 0, stream>>>(
      x, pos, W_att, xb, pos4, Wt, ptcell, count, N);

  scan1<<<GTOT / 256, 256, 0, stream>>>(count, partial);
  scan2<<<1, 256, 0, stream>>>(partial, cell_start);
  scan3<<<GTOT / 256, 256, 0, stream>>>(count, partial, cell_start, cursor);

  scatter_kernel<<<(N + 255) / 256, 256, 0, stream>>>(pos4, ptcell, cursor,
                                                      spos4, sid, N);

  knn_grid<<<(M + 3) / 4, 256, 0, stream>>>(pos4, spos4, sid, cell_start, idx,
                                            nbr, M);

  mid_kernel<<<(M + 7) / 8, 256, 0, stream>>>(xb, pos4, idx, W_pos, b_pos, Wt,
                                              b_att, nbr, aggr, M);
  out_kernel<<<(M + 15) / 16, 256, 0, stream>>>(aggr, W_glob, b_glob, out, M);
}

// Round 8
// 202.278 us; speedup vs baseline: 529.9168x; 1.0481x over previous
//
#include <hip/hip_runtime.h>
#include <stdint.h>

#define KNB   16
#define GD    64                    // grid cells per axis
#define GTOT  (GD * GD * GD)        // 262144 cells
#define GORIG (-6.5f)
#define GEDGE 0.203125f             // 13.0 / 64
#define GINV  (1.0f / GEDGE)
#define CAPW  640                   // per-query candidate capacity (10 x 64)

typedef short short8 __attribute__((ext_vector_type(8)));
typedef float floatx4 __attribute__((ext_vector_type(4)));

__device__ __forceinline__ unsigned short f2bf(float x) {
  union { float f; uint32_t u; } v; v.f = x;
  uint32_t u = v.u + 0x7FFFu + ((v.u >> 16) & 1u);   // RNE
  return (unsigned short)(u >> 16);
}
__device__ __forceinline__ float bf2f(unsigned short b) {
  return __uint_as_float(((uint32_t)b) << 16);
}
__device__ __forceinline__ int cellco(float v) {
  int c = (int)floorf((v - GORIG) * GINV);
  return c < 0 ? 0 : (c > GD - 1 ? GD - 1 : c);
}

// ---------------------------------------------------------------------------
// zero: count[GTOT] = 0  (must run before prep's atomics, every launch)
// ---------------------------------------------------------------------------
__global__ void zero_kernel(int* __restrict__ count) {
  int i = (blockIdx.x * 256 + threadIdx.x) * 4;
  *(int4*)(count + i) = make_int4(0, 0, 0, 0);
}

// ---------------------------------------------------------------------------
// prep: xb = bf16(x); pos4 = {x,y,z,pp}; ptcell[j] + count atomics; Wt.
// ---------------------------------------------------------------------------
__global__ void prep_kernel(const float* __restrict__ x,
                            const float* __restrict__ pos,
                            const float* __restrict__ W_att,
                            unsigned short* __restrict__ xb,
                            float4* __restrict__ pos4,
                            unsigned short* __restrict__ Wt,
                            int* __restrict__ ptcell,
                            int* __restrict__ count, int N) {
  int id = blockIdx.x * 256 + threadIdx.x;
  int nx8 = N * 8;
  if (id < nx8) {
    const float4* src = (const float4*)x + (size_t)id * 2;
    float4 a = src[0], b = src[1];
    short8 v;
    v[0] = (short)f2bf(a.x); v[1] = (short)f2bf(a.y);
    v[2] = (short)f2bf(a.z); v[3] = (short)f2bf(a.w);
    v[4] = (short)f2bf(b.x); v[5] = (short)f2bf(b.y);
    v[6] = (short)f2bf(b.z); v[7] = (short)f2bf(b.w);
    *(short8*)(xb + (size_t)id * 8) = v;
  } else if (id < nx8 + N) {
    int j = id - nx8;
    float px = pos[3 * j], py = pos[3 * j + 1], pz = pos[3 * j + 2];
    float pp = fmaf(px, px, fmaf(py, py, pz * pz));
    pos4[j] = make_float4(px, py, pz, pp);
    int cid = (cellco(pz) * GD + cellco(py)) * GD + cellco(px);
    ptcell[j] = cid;
    atomicAdd(&count[cid], 1);
  } else if (id < nx8 + N + 128 * 128) {
    int t = id - nx8 - N;
    int c = t >> 7, f = t & 127;
    Wt[f * 128 + c] = f2bf(W_att[t]);
  }
}

// ---------------------------------------------------------------------------
// two-level exclusive scan of count[GTOT] -> cell_start / cursor
// ---------------------------------------------------------------------------
__global__ __launch_bounds__(256) void scan1(const int* __restrict__ count,
                                             int* __restrict__ partial) {
  int b = blockIdx.x, t = threadIdx.x;
  int v = count[b * 256 + t];
#pragma unroll
  for (int off = 1; off < 64; off <<= 1) v += __shfl_xor(v, off);
  __shared__ int ws_[4];
  if ((t & 63) == 0) ws_[t >> 6] = v;
  __syncthreads();
  if (t == 0) partial[b] = ws_[0] + ws_[1] + ws_[2] + ws_[3];
}

__global__ __launch_bounds__(256) void scan2(int* __restrict__ partial,
                                             int* __restrict__ cell_start) {
  int t = threadIdx.x;
  int v0 = partial[t * 4], v1 = partial[t * 4 + 1];
  int v2 = partial[t * 4 + 2], v3 = partial[t * 4 + 3];
  int s1 = v0 + v1, s2 = s1 + v2, s3 = s2 + v3;
  int x = s3;
  int lane = t & 63, wv = t >> 6;
#pragma unroll
  for (int off = 1; off < 64; off <<= 1) {
    int y = __shfl_up(x, off);
    if (lane >= off) x += y;
  }
  __shared__ int wsum[4];
  if (lane == 63) wsum[wv] = x;
  __syncthreads();
  int base = 0;
  for (int k = 0; k < wv; ++k) base += wsum[k];
  int excl = base + x - s3;
  partial[t * 4]     = excl;
  partial[t * 4 + 1] = excl + v0;
  partial[t * 4 + 2] = excl + s1;
  partial[t * 4 + 3] = excl + s2;
  if (t == 255) cell_start[GTOT] = excl + s3;   // = N
}

__global__ __launch_bounds__(256) void scan3(const int* __restrict__ count,
                                             const int* __restrict__ partial,
                                             int* __restrict__ cell_start,
                                             int* __restrict__ cursor) {
  int b = blockIdx.x, t = threadIdx.x;
  int v = count[b * 256 + t];
  int x = v;
  int lane = t & 63, wv = t >> 6;
#pragma unroll
  for (int off = 1; off < 64; off <<= 1) {
    int y = __shfl_up(x, off);
    if (lane >= off) x += y;
  }
  __shared__ int wsum[4];
  if (lane == 63) wsum[wv] = x;
  __syncthreads();
  int base = partial[b];
  for (int k = 0; k < wv; ++k) base += wsum[k];
  int excl = base + x - v;
  cell_start[b * 256 + t] = excl;
  cursor[b * 256 + t] = excl;
}

// ---------------------------------------------------------------------------
// scatter: points into cell-sorted order (spos4 + original index sid)
// ---------------------------------------------------------------------------
__global__ void scatter_kernel(const float4* __restrict__ pos4,
                               const int* __restrict__ ptcell,
                               int* __restrict__ cursor,
                               float4* __restrict__ spos4,
                               int* __restrict__ sid, int N) {
  int j = blockIdx.x * 256 + threadIdx.x;
  if (j >= N) return;
  int cid = ptcell[j];
  int slot = atomicAdd(&cursor[cid], 1);
  spos4[slot] = pos4[j];
  sid[slot] = j;
}

// ---------------------------------------------------------------------------
// knn_grid (R8): one wave per query. Shell s enumerated as (2s+1)^2 (dz,dy)
// rows (full contiguous x-row when perimeter / s==1; else two singletons).
// NEW: flattened cooperative drain -- per 64-pair batch, wave prefix-sum of
// row lengths -> ps[65] in LDS + (stA,lA,stB); points processed in chunks of
// 64 with a 6-step binary search mapping flat index -> (row lane, offset).
// Full lane utilization regardless of row sparsity. Candidate order changes
// but the algorithm is order-independent (exact keys). Compaction to exact
// top-16 (taukey = 16th key) before any chunk that could overflow -> tot <=
// CAPW invariant. Termination when >=16 stored lie within r_expl (distance
// to unexplored region; grid-clamped sides = inf). Extraction = proven
// extract-min machinery.
// ---------------------------------------------------------------------------
__global__ __launch_bounds__(256) void knn_grid(
    const float4* __restrict__ pos4, const float4* __restrict__ spos4,
    const int* __restrict__ sid, const int* __restrict__ cell_start,
    const int* __restrict__ idx, int* __restrict__ nbr, int M) {
  __shared__ unsigned long long cand[4][CAPW];
  __shared__ uint32_t rsA[4][64], rlA[4][64], rsB[4][64];
  __shared__ uint32_t rps[4][72];   // ps[0..64], padded
  const int tid = threadIdx.x, wv = tid >> 6, ln = tid & 63;
  const int m = blockIdx.x * 4 + wv;
  if (m >= M) return;

  const float4 qp = pos4[idx[m]];
  const int cqx = cellco(qp.x), cqy = cellco(qp.y), cqz = cellco(qp.z);

  int tot = 0;
  unsigned long long taukey = ~0ull;   // store filter (max until first compact)
  bool done = false;
  for (int s = 1; s <= 64 && !done; ++s) {
    const int w = 2 * s + 1, npair = w * w;
    for (int base = 0; base < npair; base += 64) {
      int i = base + ln;
      int stA = 0, lA = 0, stB = 0, lB = 0;
      if (i < npair) {
        int dz = i / w - s, dy = i - (i / w) * w - s;
        int cz = cqz + dz, cy = cqy + dy;
        if (cz >= 0 && cz < GD && cy >= 0 && cy < GD) {
          int rowbase = (cz * GD + cy) * GD;
          int az = dz < 0 ? -dz : dz, ay = dy < 0 ? -dy : dy;
          int ch = az > ay ? az : ay;
          if (s == 1 || ch == s) {
            // full contiguous x-row [cqx-s, cqx+s] clipped
            int x0 = cqx - s; if (x0 < 0) x0 = 0;
            int x1 = cqx + s; if (x1 > GD - 1) x1 = GD - 1;
            stA = cell_start[rowbase + x0];
            lA  = cell_start[rowbase + x1 + 1] - stA;
          } else {
            // interior row: two singleton cells at dx = -s, +s
            int xl = cqx - s, xr = cqx + s;
            if (xl >= 0) {
              stA = cell_start[rowbase + xl];
              lA  = cell_start[rowbase + xl + 1] - stA;
            }
            if (xr <= GD - 1) {
              stB = cell_start[rowbase + xr];
              lB  = cell_start[rowbase + xr + 1] - stB;
            }
          }
        }
      }
      // wave prefix sum of per-lane lengths -> flat layout
      int len = lA + lB;
      int xinc = len;
#pragma unroll
      for (int off = 1; off < 64; off <<= 1) {
        int y = __shfl_up(xinc, off);
        if (ln >= off) xinc += y;
      }
      int T = __shfl(xinc, 63);
      if (T == 0) continue;
      rps[wv][ln] = (uint32_t)(xinc - len);   // exclusive prefix
      if (ln == 63) rps[wv][64] = (uint32_t)T;
      rsA[wv][ln] = (uint32_t)stA;
      rlA[wv][ln] = (uint32_t)lA;
      rsB[wv][ln] = (uint32_t)stB;

      for (int b2 = 0; b2 < T; b2 += 64) {
        // --- overflow-proof: compact to exact top-16 before store ---
        if (tot + 64 > CAPW) {
          unsigned long long c[CAPW / 64];
#pragma unroll
          for (int chk = 0; chk < CAPW / 64; ++chk) {
            int slot = chk * 64 + ln;
            c[chk] = (slot < tot) ? cand[wv][slot] : ~0ull;
          }
          unsigned long long last = 0;
#pragma unroll
          for (int r = 0; r < KNB; ++r) {
            unsigned long long mn = c[0];
#pragma unroll
            for (int chk = 1; chk < CAPW / 64; ++chk)
              mn = (c[chk] < mn) ? c[chk] : mn;
#pragma unroll
            for (int off = 1; off < 64; off <<= 1) {
              unsigned long long o = __shfl_xor(mn, off);
              mn = (o < mn) ? o : mn;
            }
            if (ln == 0) cand[wv][r] = mn;
            last = mn;
#pragma unroll
            for (int chk = 0; chk < CAPW / 64; ++chk)
              if (c[chk] == mn) c[chk] = ~0ull;
          }
          tot = KNB;
          taukey = last;
        }
        int flat = b2 + ln;
        unsigned long long key = ~0ull;
        bool ok = false;
        if (flat < T) {
          // binary search: largest l with ps[l] <= flat (zero-len lanes
          // auto-skipped since ps[l]==ps[l+1])
          int lo = 0;
#pragma unroll
          for (int step = 32; step > 0; step >>= 1) {
            int mid = lo + step;
            if (mid <= 63 && (int)rps[wv][mid] <= flat) lo = mid;
          }
          int o = flat - (int)rps[wv][lo];
          uint32_t sa = rsA[wv][lo], la = rlA[wv][lo];
          int p = (o < (int)la) ? (int)(sa + o)
                                : (int)(rsB[wv][lo] + (uint32_t)(o - (int)la));
          float4 pj = spos4[p];
          float dot = fmaf(qp.x, pj.x, fmaf(qp.y, pj.y, qp.z * pj.z));
          float tt  = fmaf(-2.f, dot, pj.w);
          float d2  = fmaxf(qp.w + tt, 0.f);
          key = ((unsigned long long)__float_as_uint(d2) << 32) |
                (uint32_t)sid[p];
          ok = key < taukey;
        }
        unsigned long long bm = __ballot(ok);
        int pos = __popcll(bm & ((1ull << ln) - 1ull));
        if (ok) cand[wv][tot + pos] = key;
        tot += __popcll(bm);
      }
    }
    // termination: distance from q to unexplored region (clamped side = inf)
    if (tot >= KNB) {
      float fx = qp.x - GORIG, fy = qp.y - GORIG, fz = qp.z - GORIG;
      float r = 3.0e38f;
      if (cqx - s > 0)      r = fminf(r, fx - (float)(cqx - s) * GEDGE);
      if (cqx + s < GD - 1) r = fminf(r, (float)(cqx + s + 1) * GEDGE - fx);
      if (cqy - s > 0)      r = fminf(r, fy - (float)(cqy - s) * GEDGE);
      if (cqy + s < GD - 1) r = fminf(r, (float)(cqy + s + 1) * GEDGE - fy);
      if (cqz - s > 0)      r = fminf(r, fz - (float)(cqz - s) * GEDGE);
      if (cqz + s < GD - 1) r = fminf(r, (float)(cqz + s + 1) * GEDGE - fz);
      float r2 = (r > 1.0e19f) ? 3.0e38f : r * r;
      int cnt = 0;
      for (int chk = 0; chk * 64 < tot; ++chk) {
        int slot = chk * 64 + ln;
        unsigned long long key = cand[wv][slot];
        float d2v = __uint_as_float((uint32_t)(key >> 32));
        cnt += __popcll(__ballot(slot < tot && d2v <= r2));
      }
      if (cnt >= KNB) done = true;
    }
  }

  // extraction (proven machinery)
  int nc = tot;
  unsigned long long c[CAPW / 64];
#pragma unroll
  for (int chk = 0; chk < CAPW / 64; ++chk) {
    int slot = chk * 64 + ln;
    unsigned long long k2 = cand[wv][slot];
    c[chk] = (slot < nc) ? k2 : ~0ull;
  }
#pragma unroll
  for (int r = 0; r < KNB; ++r) {
    unsigned long long mn = c[0];
#pragma unroll
    for (int chk = 1; chk < CAPW / 64; ++chk) mn = (c[chk] < mn) ? c[chk] : mn;
#pragma unroll
    for (int off = 1; off < 64; off <<= 1) {
      unsigned long long o = __shfl_xor(mn, off);
      mn = (o < mn) ? o : mn;
    }
    if (ln == 0) nbr[m * KNB + r] = (int)(uint32_t)mn;
#pragma unroll
    for (int chk = 0; chk < CAPW / 64; ++chk)
      if (c[chk] == mn) c[chk] = ~0ull;
  }
}

// ---------------------------------------------------------------------------
// mid: 8 queries / 256-thread block (unchanged from passing version).
// ---------------------------------------------------------------------------
__global__ __launch_bounds__(256) void mid_kernel(
    const unsigned short* __restrict__ xb, const float4* __restrict__ pos4,
    const int* __restrict__ idx, const float* __restrict__ W_pos,
    const float* __restrict__ b_pos, const unsigned short* __restrict__ Wt,
    const float* __restrict__ b_att, const int* __restrict__ nbr,
    float* __restrict__ aggr, int M) {
  __shared__ __align__(16) unsigned short fijb[8][16][136];
  __shared__ int nbr_s[128];
  __shared__ float4 qpos_s[8];

  const int tid = threadIdx.x;
  const int wid = tid >> 6, lane = tid & 63;
  const int col = lane & 15, quad = lane >> 4;
  const int b = blockIdx.x;

  if (tid < 128) {
    int mq = b * 8 + (tid >> 4); if (mq >= M) mq = M - 1;
    nbr_s[tid] = nbr[mq * 16 + (tid & 15)];
  }
  if (tid < 8) {
    int mq = b * 8 + tid; if (mq >= M) mq = M - 1;
    qpos_s[tid] = pos4[idx[mq]];
  }
  float wp[10];
#pragma unroll
  for (int t = 0; t < 10; ++t) wp[t] = W_pos[t * 64 + lane];
  float bp = b_pos[lane];
  __syncthreads();

  {
    int rr = tid >> 1, h = tid & 1;
    int jn = nbr_s[rr];
    const short8* src = (const short8*)(xb + ((size_t)jn << 6) + (h << 5));
    short8 v0 = src[0], v1 = src[1], v2 = src[2], v3 = src[3];
    short8* dst = (short8*)&fijb[rr >> 4][rr & 15][h * 32];
    dst[0] = v0; dst[1] = v1; dst[2] = v2; dst[3] = v3;
  }
#pragma unroll
  for (int qi = 0; qi < 2; ++qi) {
    int q = wid * 2 + qi;
    float4 qp = qpos_s[q];
#pragma unroll 4
    for (int k = 0; k < 16; ++k) {
      int jn = nbr_s[q * 16 + k];
      float4 pj = pos4[jn];
      float vx = qp.x - pj.x, vy = qp.y - pj.y, vz = qp.z - pj.z;
      float dd = sqrtf(fmaf(vx, vx, fmaf(vy, vy, vz * vz)));
      float r = bp;
      r = fmaf(qp.x, wp[0], r); r = fmaf(qp.y, wp[1], r); r = fmaf(qp.z, wp[2], r);
      r = fmaf(pj.x, wp[3], r); r = fmaf(pj.y, wp[4], r); r = fmaf(pj.z, wp[5], r);
      r = fmaf(vx, wp[6], r);  r = fmaf(vy, wp[7], r);  r = fmaf(vz, wp[8], r);
      r = fmaf(dd, wp[9], r);
      r = fmaxf(r, 0.f);
      fijb[q][k][64 + lane] = f2bf(r);
    }
  }
  __syncthreads();

#pragma unroll 1
  for (int qi = 0; qi < 2; ++qi) {
    int q = wid * 2 + qi;
    int mq = b * 8 + q;

    short8 af[4];
#pragma unroll
    for (int cs = 0; cs < 4; ++cs)
      af[cs] = *(const short8*)&fijb[q][col][cs * 32 + quad * 8];

    floatx4 acc[8];
#pragma unroll
    for (int ft = 0; ft < 8; ++ft) {
      float bav = b_att[ft * 16 + col];
      floatx4 a = {bav, bav, bav, bav};
#pragma unroll
      for (int cs = 0; cs < 4; ++cs) {
        short8 bfrag =
            *(const short8*)&Wt[(ft * 16 + col) * 128 + cs * 32 + quad * 8];
        a = __builtin_amdgcn_mfma_f32_16x16x32_bf16(af[cs], bfrag, a, 0, 0, 0);
      }
      acc[ft] = a;
    }

    float rowmax[4], rowinv[4];
#pragma unroll
    for (int r = 0; r < 4; ++r) {
      float mx = acc[0][r];
#pragma unroll
      for (int ft = 1; ft < 8; ++ft) mx = fmaxf(mx, acc[ft][r]);
      mx = fmaxf(mx, __shfl_xor(mx, 1));
      mx = fmaxf(mx, __shfl_xor(mx, 2));
      mx = fmaxf(mx, __shfl_xor(mx, 4));
      mx = fmaxf(mx, __shfl_xor(mx, 8));
      float sm = 0.f;
#pragma unroll
      for (int ft = 0; ft < 8; ++ft) sm += __expf(acc[ft][r] - mx);
      sm += __shfl_xor(sm, 1);
      sm += __shfl_xor(sm, 2);
      sm += __shfl_xor(sm, 4);
      sm += __shfl_xor(sm, 8);
      rowmax[r] = mx;
      rowinv[r] = 1.0f / sm;
    }

#pragma unroll
    for (int ft = 0; ft < 8; ++ft) {
      float ap = 0.f;
#pragma unroll
      for (int r = 0; r < 4; ++r) {
        float s = __expf(acc[ft][r] - rowmax[r]) * rowinv[r];
        float fv = bf2f(fijb[q][quad * 4 + r][ft * 16 + col]);
        ap = fmaf(s, fv, ap);
      }
      ap += __shfl_xor(ap, 16);
      ap += __shfl_xor(ap, 32);
      if (quad == 0 && mq < M)
        aggr[mq * 128 + ft * 16 + col] = ap * (1.0f / 16.0f);
    }
  }
}

// ---------------------------------------------------------------------------
// out = relu(aggr @ W_glob + b_glob)
// ---------------------------------------------------------------------------
__global__ __launch_bounds__(256) void out_kernel(
    const float* __restrict__ aggr, const float* __restrict__ W_glob,
    const float* __restrict__ b_glob, float* __restrict__ out, int M) {
  __shared__ float ag[16][128];
  const int tid = threadIdx.x;
  const int mbase = blockIdx.x * 16;
  for (int s = tid; s < 16 * 128; s += 256) {
    int r = s >> 7, cc = s & 127;
    int m = mbase + r;
    ((float*)ag)[s] = (m < M) ? aggr[m * 128 + cc] : 0.0f;
  }
  __syncthreads();
  const int f = tid & 127, h = tid >> 7;
  float acc[8];
  float bg = b_glob[f];
#pragma unroll
  for (int i = 0; i < 8; ++i) acc[i] = bg;
  for (int c = 0; c < 128; c += 4) {
    float w0 = W_glob[(c + 0) * 128 + f];
    float w1 = W_glob[(c + 1) * 128 + f];
    float w2 = W_glob[(c + 2) * 128 + f];
    float w3 = W_glob[(c + 3) * 128 + f];
#pragma unroll
    for (int i = 0; i < 8; ++i) {
      const floatx4 a4 = *(const floatx4*)&ag[h * 8 + i][c];
      acc[i] += a4[0] * w0 + a4[1] * w1 + a4[2] * w2 + a4[3] * w3;
    }
  }
#pragma unroll
  for (int i = 0; i < 8; ++i) {
    int m = mbase + h * 8 + i;
    if (m < M) out[m * 128 + f] = fmaxf(acc[i], 0.0f);
  }
}

// ---------------------------------------------------------------------------
extern "C" void kernel_launch(void* const* d_in, const int* in_sizes, int n_in,
                              void* d_out, int out_size, void* d_ws,
                              size_t ws_size, hipStream_t stream) {
  const float* x      = (const float*)d_in[0];
  const float* pos    = (const float*)d_in[1];
  const int*   idx    = (const int*)d_in[2];
  const float* W_pos  = (const float*)d_in[3];
  const float* b_pos  = (const float*)d_in[4];
  const float* W_att  = (const float*)d_in[5];
  const float* b_att  = (const float*)d_in[6];
  const float* W_glob = (const float*)d_in[7];
  const float* b_glob = (const float*)d_in[8];
  float* out = (float*)d_out;

  const int N = in_sizes[1] / 3;
  const int M = in_sizes[2];

  char* ws = (char*)d_ws;
  size_t o = 0;
  float4* pos4 = (float4*)(ws + o);               o += ((size_t)N * 16 + 255) & ~(size_t)255;
  unsigned short* xb = (unsigned short*)(ws + o); o += ((size_t)N * 128 + 255) & ~(size_t)255;
  unsigned short* Wt = (unsigned short*)(ws + o); o += (128 * 128 * 2 + 255) & ~(size_t)255;
  int* nbr = (int*)(ws + o);                      o += (((size_t)M * KNB * 4) + 255) & ~(size_t)255;
  int* ptcell = (int*)(ws + o);                   o += (((size_t)N * 4) + 255) & ~(size_t)255;
  int* count = (int*)(ws + o);                    o += ((size_t)GTOT * 4 + 255) & ~(size_t)255;
  int* cursor = (int*)(ws + o);                   o += ((size_t)GTOT * 4 + 255) & ~(size_t)255;
  int* cell_start = (int*)(ws + o);               o += ((size_t)(GTOT + 1) * 4 + 255) & ~(size_t)255;
  int* partial = (int*)(ws + o);                  o += (1024 * 4 + 255) & ~(size_t)255;
  float4* spos4 = (float4*)(ws + o);              o += ((size_t)N * 16 + 255) & ~(size_t)255;
  int* sid = (int*)(ws + o);                      o += (((size_t)N * 4) + 255) & ~(size_t)255;
  float* aggr = (float*)(ws + o);                 o += ((size_t)M * 128 * 4 + 255) & ~(size_t)255;

  zero_kernel<<<GTOT / 1024, 256, 0, stream>>>(count);

  int prep_ids = N * 8 + N + 128 * 128;
  prep_kernel<<<(prep_ids + 255) / 256, 256, 0, stream>>>(
      x, pos, W_att, xb, pos4, Wt, ptcell, count, N);

  scan1<<<GTOT / 256, 256, 0, stream>>>(count, partial);
  scan2<<<1, 256, 0, stream>>>(partial, cell_start);
  scan3<<<GTOT / 256, 256, 0, stream>>>(count, partial, cell_start, cursor);

  scatter_kernel<<<(N + 255) / 256, 256, 0, stream>>>(pos4, ptcell, cursor,
                                                      spos4, sid, N);

  knn_grid<<<(M + 3) / 4, 256, 0, stream>>>(pos4, spos4, sid, cell_start, idx,
                                            nbr, M);

  mid_kernel<<<(M + 7) / 8, 256, 0, stream>>>(xb, pos4, idx, W_pos, b_pos, Wt,
                                              b_att, nbr, aggr, M);
  out_kernel<<<(M + 15) / 16, 256, 0, stream>>>(aggr, W_glob, b_glob, out, M);
}